// Round 1
// baseline (59.539 us; speedup 1.0000x reference)
//
#include <hip/hip_runtime.h>

constexpr int OBS   = 682;   // 210 view + 32 feat + 440 nb
constexpr int AG    = 20;
constexpr int ACTN  = 21;
constexpr int C1W_N = 1440;  // 32*5*3*3
constexpr int C2W_N = 9216;  // 32*32*3*3

// Transpose conv weights: [oc][k] -> [k][oc]  (k = c*9 + kh*3 + kw)
__global__ void transpose_w_k(const float* __restrict__ c1w,
                              const float* __restrict__ c2w,
                              float* __restrict__ ws) {
    int idx = blockIdx.x * 256 + threadIdx.x;
    if (idx < C1W_N) {
        int oc = idx / 45, x = idx - oc * 45;
        ws[x * 32 + oc] = c1w[idx];
    }
    int i2 = idx - C1W_N;
    if (i2 >= 0 && i2 < C2W_N) {
        int oc = i2 / 288, x = i2 - oc * 288;
        ws[C1W_N + x * 32 + oc] = c2w[i2];
    }
}

template <bool TW>
__global__ __launch_bounds__(64, 4) void fused_k(
    const float* __restrict__ obs,
    const float* __restrict__ c1w, const float* __restrict__ c1b,
    const float* __restrict__ c2w, const float* __restrict__ c2b,
    const float* __restrict__ f1w, const float* __restrict__ f1b,
    const float* __restrict__ f2w, const float* __restrict__ f2b,
    const float* __restrict__ f3w, const float* __restrict__ f3b,
    const float* __restrict__ wt,
    float* __restrict__ out)
{
    const int b = blockIdx.x;
    const int t = threadIdx.x;

    __shared__ __align__(16) float s_obs[OBS]; // [0,210) view, [210,242) feat, [242,682) nb
    __shared__ __align__(16) float s_c1[640];  // [ic][h=5][w=4]
    __shared__ __align__(16) float s_c2[192];  // [oc][pos=6]
    __shared__ __align__(16) float s_x[64];
    __shared__ __align__(16) float s_h[64];

    const float* orow = obs + (long)b * OBS;
    for (int i = t; i < OBS; i += 64) s_obs[i] = orow[i];
    __syncthreads();

    // ---------------- conv1: (5,7,6) -> (32,5,4), relu ----------------
    {
        const int oc = t & 31, ph = t >> 5;   // this thread: ow in {ph, ph+2}, all oh
        float acc[10];                         // [oh][owi]
        #pragma unroll
        for (int i = 0; i < 10; ++i) acc[i] = 0.f;
        #pragma unroll
        for (int c = 0; c < 5; ++c) {
            float w[9];
            #pragma unroll
            for (int k = 0; k < 9; ++k)
                w[k] = TW ? wt[(c * 9 + k) * 32 + oc] : c1w[oc * 45 + c * 9 + k];
            #pragma unroll
            for (int r = 0; r < 7; ++r) {
                float rv[5];
                #pragma unroll
                for (int j = 0; j < 5; ++j) rv[j] = s_obs[c * 42 + r * 6 + ph + j];
                #pragma unroll
                for (int kh = 0; kh < 3; ++kh) {
                    int oh = r - kh;
                    if (oh < 0 || oh > 4) continue;      // compile-time after unroll
                    #pragma unroll
                    for (int kw = 0; kw < 3; ++kw) {
                        acc[oh * 2 + 0] = fmaf(rv[kw],     w[kh * 3 + kw], acc[oh * 2 + 0]);
                        acc[oh * 2 + 1] = fmaf(rv[kw + 2], w[kh * 3 + kw], acc[oh * 2 + 1]);
                    }
                }
            }
        }
        float bias = c1b[oc];
        #pragma unroll
        for (int oh = 0; oh < 5; ++oh)
            #pragma unroll
            for (int owi = 0; owi < 2; ++owi)
                s_c1[oc * 20 + oh * 4 + ph + 2 * owi] = fmaxf(acc[oh * 2 + owi] + bias, 0.f);
    }
    __syncthreads();

    // ---------------- conv2: (32,5,4) -> (32,3,2), relu ----------------
    if (t < 32) {
        const int oc = t;
        float acc[6];                          // [oh][ow]
        #pragma unroll
        for (int i = 0; i < 6; ++i) acc[i] = 0.f;
        #pragma unroll 4
        for (int ic = 0; ic < 32; ++ic) {
            const float4* rp = (const float4*)&s_c1[ic * 20];
            float4 row[5];
            #pragma unroll
            for (int r = 0; r < 5; ++r) row[r] = rp[r];
            float w[9];
            #pragma unroll
            for (int k = 0; k < 9; ++k)
                w[k] = TW ? wt[C1W_N + (ic * 9 + k) * 32 + oc] : c2w[oc * 288 + ic * 9 + k];
            #pragma unroll
            for (int kh = 0; kh < 3; ++kh)
                #pragma unroll
                for (int kw = 0; kw < 3; ++kw) {
                    float ww = w[kh * 3 + kw];
                    #pragma unroll
                    for (int oh = 0; oh < 3; ++oh) {
                        float4 rr = row[oh + kh];
                        float v0 = (kw == 0) ? rr.x : (kw == 1) ? rr.y : rr.z;
                        float v1 = (kw == 0) ? rr.y : (kw == 1) ? rr.z : rr.w;
                        acc[oh * 2 + 0] = fmaf(v0, ww, acc[oh * 2 + 0]);
                        acc[oh * 2 + 1] = fmaf(v1, ww, acc[oh * 2 + 1]);
                    }
                }
        }
        float bias = c2b[oc];
        #pragma unroll
        for (int p = 0; p < 6; ++p)
            s_c2[oc * 6 + p] = fmaxf(acc[p] + bias, 0.f);
    }
    __syncthreads();

    // ---------------- fc1: 192 -> 64, relu ----------------
    {
        float acc = f1b[t];
        #pragma unroll 4
        for (int i4 = 0; i4 < 48; ++i4) {
            float4 v = ((const float4*)s_c2)[i4];
            acc = fmaf(v.x, f1w[(i4 * 4 + 0) * 64 + t], acc);
            acc = fmaf(v.y, f1w[(i4 * 4 + 1) * 64 + t], acc);
            acc = fmaf(v.z, f1w[(i4 * 4 + 2) * 64 + t], acc);
            acc = fmaf(v.w, f1w[(i4 * 4 + 3) * 64 + t], acc);
        }
        s_x[t] = fmaxf(acc, 0.f);
    }
    __syncthreads();

    // ---------------- base = x@W2x + feat@W2f + b2 ----------------
    float base_t;
    {
        const float* W2x = f2w;             // rows [0,64)
        const float* W2f = f2w + 64 * 64;   // rows [64,96)
        float acc = f2b[t];
        #pragma unroll 4
        for (int i4 = 0; i4 < 16; ++i4) {
            float4 v = ((const float4*)s_x)[i4];
            acc = fmaf(v.x, W2x[(i4 * 4 + 0) * 64 + t], acc);
            acc = fmaf(v.y, W2x[(i4 * 4 + 1) * 64 + t], acc);
            acc = fmaf(v.z, W2x[(i4 * 4 + 2) * 64 + t], acc);
            acc = fmaf(v.w, W2x[(i4 * 4 + 3) * 64 + t], acc);
        }
        const float2* fp = (const float2*)&s_obs[210];   // feat, 8B-aligned
        #pragma unroll 4
        for (int i2 = 0; i2 < 16; ++i2) {
            float2 v = fp[i2];
            acc = fmaf(v.x, W2f[(i2 * 2 + 0) * 64 + t], acc);
            acc = fmaf(v.y, W2f[(i2 * 2 + 1) * 64 + t], acc);
        }
        base_t = acc;
    }

    // ---------------- agents: accumulate h over 20 agents ----------------
    const float* W2id  = f2w + 96 * 64;
    const float* W2act = f2w + 116 * 64;
    float hacc = 0.f;
    float cnt  = 0.f;
    for (int a = 0; a < AG; ++a) {
        float idf = s_obs[242 + a * 22];
        int id = (int)idf;                 // exact small ints
        if (id < -1) continue;             // invalid -> contributes 0 (uniform branch)
        float u = base_t + ((id >= 0) ? W2id[id * 64 + t] : 0.f);
        bool az = true;
        float at = 0.f;
        #pragma unroll
        for (int j = 0; j < ACTN; ++j) {
            float av = s_obs[242 + a * 22 + 1 + j];
            az = az && (av == 0.f);
            at = fmaf(av, W2act[j * 64 + t], at);
        }
        if ((id >= 0) && az) {
            // expand: sum_j relu(u + W2act[j])  (q_e factorization)
            #pragma unroll
            for (int j = 0; j < ACTN; ++j)
                hacc += fmaxf(u + W2act[j * 64 + t], 0.f);
            cnt += 21.f;
        } else {
            hacc += fmaxf(u + at, 0.f);
            cnt += 1.f;
        }
    }
    s_h[t] = hacc;
    __syncthreads();

    // ---------------- final: q = hacc @ fc3_w + cnt*fc3_b ----------------
    if (t < 21) {
        float q = cnt * f3b[t];
        #pragma unroll 4
        for (int h4 = 0; h4 < 16; ++h4) {
            float4 v = ((const float4*)s_h)[h4];
            q = fmaf(v.x, f3w[(h4 * 4 + 0) * 21 + t], q);
            q = fmaf(v.y, f3w[(h4 * 4 + 1) * 21 + t], q);
            q = fmaf(v.z, f3w[(h4 * 4 + 2) * 21 + t], q);
            q = fmaf(v.w, f3w[(h4 * 4 + 3) * 21 + t], q);
        }
        out[b * 21 + t] = q;
    }
}

extern "C" void kernel_launch(void* const* d_in, const int* in_sizes, int n_in,
                              void* d_out, int out_size, void* d_ws, size_t ws_size,
                              hipStream_t stream) {
    const float* obs = (const float*)d_in[0];
    const float* c1w = (const float*)d_in[1];
    const float* c1b = (const float*)d_in[2];
    const float* c2w = (const float*)d_in[3];
    const float* c2b = (const float*)d_in[4];
    const float* f1w = (const float*)d_in[5];
    const float* f1b = (const float*)d_in[6];
    const float* f2w = (const float*)d_in[7];
    const float* f2b = (const float*)d_in[8];
    const float* f3w = (const float*)d_in[9];
    const float* f3b = (const float*)d_in[10];
    float* ws = (float*)d_ws;
    float* o  = (float*)d_out;

    const bool tw = ws_size >= (size_t)(C1W_N + C2W_N) * sizeof(float);
    if (tw) {
        transpose_w_k<<<(C1W_N + C2W_N + 255) / 256, 256, 0, stream>>>(c1w, c2w, ws);
        fused_k<true><<<4096, 64, 0, stream>>>(obs, c1w, c1b, c2w, c2b, f1w, f1b,
                                               f2w, f2b, f3w, f3b, ws, o);
    } else {
        fused_k<false><<<4096, 64, 0, stream>>>(obs, c1w, c1b, c2w, c2b, f1w, f1b,
                                                f2w, f2b, f3w, f3b, ws, o);
    }
}